// Round 4
// baseline (1332.879 us; speedup 1.0000x reference)
//
#include <hip/hip_runtime.h>
#include <math.h>
#include <stdint.h>

#define SEQ 4096
#define DIM 1024
#define NB  4

typedef __attribute__((ext_vector_type(8))) __bf16 bf16x8;
typedef __attribute__((ext_vector_type(4))) float  f32x4;
typedef __attribute__((ext_vector_type(4))) float  floatx4;
typedef __attribute__((ext_vector_type(8))) unsigned short ushortx8;
typedef __attribute__((ext_vector_type(4))) unsigned short ushortx4;

__device__ __forceinline__ unsigned short f2bf(float f){
  union { float f; unsigned int u; } c; c.f = f;
  unsigned int u = c.u;
  return (unsigned short)((u + 0x7fffu + ((u >> 16) & 1u)) >> 16);
}

__device__ __forceinline__ f32x4 mfma16(bf16x8 a, bf16x8 b, f32x4 c){
  return __builtin_amdgcn_mfma_f32_16x16x32_bf16(a, b, c, 0, 0, 0);
}

__device__ __forceinline__ void g2l16(void* lds, const void* g){
  __builtin_amdgcn_global_load_lds(
      (const __attribute__((address_space(1))) unsigned int*)g,
      (__attribute__((address_space(3))) unsigned int*)lds, 16, 0, 0);
}

#define WAITVM8 asm volatile("s_waitcnt vmcnt(8)" ::: "memory")
#define WAITVM0 asm volatile("s_waitcnt vmcnt(0)" ::: "memory")

// ---------------- fp32 -> bf16 conversion ----------------
__global__ void cvt_kernel(const float* __restrict__ src,
                           unsigned short* __restrict__ dst, int n4){
  int i = blockIdx.x * blockDim.x + threadIdx.x;
  if (i >= n4) return;
  floatx4 v = *((const floatx4*)src + i);
  ushortx4 o;
  o[0] = f2bf(v[0]); o[1] = f2bf(v[1]); o[2] = f2bf(v[2]); o[3] = f2bf(v[3]);
  *((ushortx4*)dst + i) = o;
}

// ---------------- QKV projection GEMM (m97 structure) ----------------
__global__ __launch_bounds__(256, 2) void gemm_qkv(
    const unsigned short* __restrict__ E,
    const unsigned short* __restrict__ W3,
    unsigned short* __restrict__ Qd,
    unsigned short* __restrict__ Kd,
    unsigned short* __restrict__ Vd)
{
  __shared__ unsigned short As[128][64];
  __shared__ unsigned short Bs[128][64];

  const int t  = threadIdx.x;
  const int m0 = blockIdx.y * 128;
  const int n0 = blockIdx.x * 128;
  const unsigned short* W = W3 + (size_t)blockIdx.z * (DIM * (size_t)DIM);
  unsigned short* dst = blockIdx.z == 0 ? Qd : (blockIdx.z == 1 ? Kd : Vd);

  const int l  = t & 63;
  const int w  = t >> 6;
  const int lr = l & 15;
  const int lk = l >> 4;
  const int wr = (w >> 1) * 64;
  const int wc = (w & 1) * 64;

  f32x4 acc[4][4];
  #pragma unroll
  for (int i = 0; i < 4; ++i)
    #pragma unroll
    for (int j = 0; j < 4; ++j) acc[i][j] = (f32x4)0.0f;

  for (int kt = 0; kt < DIM / 64; ++kt){
    const int k0 = kt * 64;
    #pragma unroll
    for (int c = 0; c < 4; ++c){
      int id  = c * 256 + t;
      int row = id >> 3;
      int cb  = (id & 7) * 8;
      g2l16(&As[row][cb], E + (size_t)(m0 + row) * DIM + k0 + cb);
      g2l16(&Bs[row][cb], W + (size_t)(n0 + row) * DIM + k0 + cb);
    }
    asm volatile("s_waitcnt vmcnt(0)" ::: "memory");
    __syncthreads();
    #pragma unroll
    for (int ks = 0; ks < 2; ++ks){
      bf16x8 af[4], bfr[4];
      #pragma unroll
      for (int i = 0; i < 4; ++i){
        af[i]  = *(const bf16x8*)&As[wr + i*16 + lr][ks*32 + lk*8];
        bfr[i] = *(const bf16x8*)&Bs[wc + i*16 + lr][ks*32 + lk*8];
      }
      #pragma unroll
      for (int i = 0; i < 4; ++i)
        #pragma unroll
        for (int j = 0; j < 4; ++j)
          acc[i][j] = mfma16(af[i], bfr[j], acc[i][j]);
    }
    __syncthreads();
  }
  #pragma unroll
  for (int i = 0; i < 4; ++i)
    #pragma unroll
    for (int j = 0; j < 4; ++j)
      #pragma unroll
      for (int r = 0; r < 4; ++r){
        int row = wr + i*16 + lk*4 + r;
        int col = wc + j*16 + lr;
        dst[(size_t)(m0 + row) * DIM + n0 + col] = f2bf(acc[i][j][r]);
      }
}

// ---------------- V transpose ----------------
__global__ __launch_bounds__(256) void transpose_v(
    const unsigned short* __restrict__ V, unsigned short* __restrict__ VT)
{
  __shared__ unsigned short T[64][72];
  const int b  = blockIdx.z;
  const int s0 = blockIdx.x * 64;
  const int a0 = blockIdx.y * 64;
  const unsigned short* Vb = V + (size_t)b * SEQ * DIM;
  unsigned short* VTb = VT + (size_t)b * DIM * SEQ;
  const int t = threadIdx.x;
  const int r = t >> 3, cg = t & 7;
  #pragma unroll
  for (int p = 0; p < 2; ++p){
    int row = r + p * 32;
    ushortx8 v = *(const ushortx8*)(Vb + (size_t)(s0 + row) * DIM + a0 + cg*8);
    *(ushortx8*)&T[row][cg*8] = v;
  }
  __syncthreads();
  #pragma unroll
  for (int p = 0; p < 2; ++p){
    int ar = r + p * 32;
    ushortx8 o;
    #pragma unroll
    for (int j = 0; j < 8; ++j) o[j] = T[cg*8 + j][ar];
    *(ushortx8*)(VTb + (size_t)(a0 + ar) * SEQ + s0 + cg*8) = o;
  }
}

// ---------------- flash attention v4: Q in registers, 64KB chunks ----------------
// BQ=32, BK=64. 256 blocks x 512 threads (8 waves). Tiles (127-pair, pair).
// Per KV iter: 4 phases (K0,K1 = 64x512 K-halves; V0,V1 = 512x64 VT-halves),
// each 64KB, ping-pong 2 buffers, 2-ahead, counted vmcnt(8).
// Q (32x1024) lives in per-wave registers (128 VGPR), loaded once per tile.

// chunk cc: phase p = cc&3 (0,1 = K halves; 2,3 = V halves), j = cc>>2
#define ISSUE_CHUNK(cc) do { \
  int _c = (cc); \
  if (_c < nj4){ \
    int _j = _c >> 2, _p = _c & 3; \
    char* _buf = cbuf + (size_t)(_c & 1) * 65536; \
    if (_p < 2){ \
      _Pragma("unroll") \
      for (int _u = 0; _u < 8; ++_u){ \
        int _s = _u * 512 + t; \
        int _r = _s >> 6; \
        int _o = ((_s & 63) * 16) ^ ((_r & 7) << 4); \
        g2l16(_buf + (size_t)_s * 16, \
              (const char*)(Kg + (size_t)(_j * 64 + _r) * DIM + _p * 512) + _o); \
      } \
    } else { \
      _Pragma("unroll") \
      for (int _u = 0; _u < 8; ++_u){ \
        int _s = _u * 512 + t; \
        int _r = _s >> 3; \
        int _o = ((_s & 7) * 16) ^ ((_r & 7) << 4); \
        g2l16(_buf + (size_t)_s * 16, \
              (const char*)(VTg + (size_t)((_p - 2) * 512 + _r) * SEQ + _j * 64) + _o); \
      } \
    } \
  } \
} while (0)

__global__ __launch_bounds__(512, 2) void flash_attn(
    const unsigned short* __restrict__ Q,
    const unsigned short* __restrict__ K,
    const unsigned short* __restrict__ VT,
    float* __restrict__ out)
{
  __shared__ char cbufRaw[131072];  // 2 x 64KB ping-pong
  __shared__ float Ss[32][68];
  __shared__ unsigned short Ps[32][72];
  __shared__ float mS[32], lS[32], aS[32];

  char* cbuf = cbufRaw;

  const int fid  = blockIdx.x;
  const int xcd  = fid & 7;
  const int b    = xcd >> 1;                      // 2 XCDs per batch
  const int pair = (fid >> 3) + (xcd & 1) * 32;   // 0..63

  const int t  = threadIdx.x;
  const int w  = t >> 6;
  const int l  = t & 63;
  const int lr = l & 15;
  const int lk = l >> 4;
  const int lk16 = lk * 16;
  const int swz  = (lr & 7) << 4;

  const unsigned short* Kg  = K  + (size_t)b * SEQ * DIM;
  const unsigned short* VTg = VT + (size_t)b * DIM * SEQ;

  const float scale = 0.03125f;  // 1/sqrt(1024)

  // phase A roles: S[32x64] = 2M x 4N frags, one per wave; wave's Q rows in regs
  const int mfa = w >> 2;
  const int nfa = w & 3;

  bf16x8 q[32];          // Q[mfa*16+lr][0..1024) : 128 VGPR
  f32x4 acc[2][2][4];    // [vphase][m][nf] : 64 VGPR

  for (int tix = 0; tix < 2; ++tix){
    const int qt = tix ? pair : (127 - pair);
    const int nj = qt / 2 + 1;
    const int nj4 = nj * 4;

    if (tix) __syncthreads();               // epilogue reads / cbuf drain done
    if (t < 32){ mS[t] = -INFINITY; lS[t] = 0.0f; }

    // load Q rows into registers (vmcnt-counted before chunk issues)
    {
      const unsigned short* Qr =
          Q + ((size_t)b * SEQ + (size_t)qt * 32 + mfa * 16 + lr) * DIM + lk * 8;
      #pragma unroll
      for (int i = 0; i < 32; ++i)
        q[i] = *(const bf16x8*)(Qr + i * 32);
    }
    ISSUE_CHUNK(0);
    ISSUE_CHUNK(1);

    #pragma unroll
    for (int vp = 0; vp < 2; ++vp)
      #pragma unroll
      for (int m = 0; m < 2; ++m)
        #pragma unroll
        for (int nf = 0; nf < 4; ++nf) acc[vp][m][nf] = (f32x4)0.0f;

    int c = 0;
    for (int j = 0; j < nj; ++j){
      f32x4 sA0 = (f32x4)0.0f, sA1 = (f32x4)0.0f;

      // ---- K phases: S += Q[:,half] K[:,half]^T ----
      #pragma unroll
      for (int kp = 0; kp < 2; ++kp){
        if (c + 1 < nj4) { WAITVM8; } else { WAITVM0; }
        __syncthreads();
        {
          const char* bB = cbuf + (size_t)(c & 1) * 65536
                               + (size_t)(nfa * 16 + lr) * 1024;
          __builtin_amdgcn_s_setprio(1);
          #pragma unroll
          for (int ks = 0; ks < 16; ks += 2){
            bf16x8 kb0 = *(const bf16x8*)(bB + ((ks * 64 + lk16) ^ swz));
            bf16x8 kb1 = *(const bf16x8*)(bB + (((ks + 1) * 64 + lk16) ^ swz));
            sA0 = mfma16(q[kp * 16 + ks],     kb0, sA0);
            sA1 = mfma16(q[kp * 16 + ks + 1], kb1, sA1);
          }
          __builtin_amdgcn_s_setprio(0);
        }
        if (kp == 1){
          f32x4 sv = sA0 + sA1;
          #pragma unroll
          for (int r = 0; r < 4; ++r)
            Ss[mfa * 16 + lk * 4 + r][nfa * 16 + lr] = sv[r];
        }
        __syncthreads();
        ISSUE_CHUNK(c + 2);
        ++c;
      }

      // ---- softmax over 32x64 tile (V loads in flight) ----
      {
        const int row = t >> 4;
        const int cg  = t & 15;
        f32x4 v0 = *(const f32x4*)&Ss[row][cg * 4];
        const int grow = qt * 32 + row;
        const int gc0  = j * 64 + cg * 4;
        float svv[4];
        #pragma unroll
        for (int i2 = 0; i2 < 4; ++i2)
          svv[i2] = (gc0 + i2 > grow) ? -INFINITY : v0[i2] * scale;
        float mx = fmaxf(fmaxf(svv[0], svv[1]), fmaxf(svv[2], svv[3]));
        #pragma unroll
        for (int d = 1; d < 16; d <<= 1) mx = fmaxf(mx, __shfl_xor(mx, d, 64));
        float mprev = mS[row];
        float mnew  = fmaxf(mprev, mx);
        float alpha = __expf(mprev - mnew);
        float sum = 0.f;
        ushortx4 pb;
        #pragma unroll
        for (int i2 = 0; i2 < 4; ++i2){
          float p = __expf(svv[i2] - mnew);
          sum += p;
          pb[i2] = f2bf(p);
        }
        #pragma unroll
        for (int d = 1; d < 16; d <<= 1) sum += __shfl_xor(sum, d, 64);
        if (cg == 0){
          mS[row] = mnew;
          lS[row] = lS[row] * alpha + sum;
          aS[row] = alpha;
        }
        *(ushortx4*)&Ps[row][cg * 4] = pb;
      }

      // ---- V phases: O[:, vp*512..] accum; wave = 32 rows x 64 d-cols ----
      #pragma unroll
      for (int vp = 0; vp < 2; ++vp){
        if (c + 1 < nj4) { WAITVM8; } else { WAITVM0; }
        __syncthreads();
        if (vp == 0){
          float al[2][4];
          #pragma unroll
          for (int m = 0; m < 2; ++m)
            #pragma unroll
            for (int r = 0; r < 4; ++r) al[m][r] = aS[m * 16 + lk * 4 + r];
          #pragma unroll
          for (int p2 = 0; p2 < 2; ++p2)
            #pragma unroll
            for (int m = 0; m < 2; ++m)
              #pragma unroll
              for (int nf = 0; nf < 4; ++nf)
                #pragma unroll
                for (int r = 0; r < 4; ++r) acc[p2][m][nf][r] *= al[m][r];
        }
        {
          const char* vB = cbuf + (size_t)(c & 1) * 65536;
          bf16x8 pa[2][2];
          #pragma unroll
          for (int m = 0; m < 2; ++m)
            #pragma unroll
            for (int ks = 0; ks < 2; ++ks)
              pa[m][ks] = *(const bf16x8*)&Ps[m * 16 + lr][ks * 32 + lk * 8];
          __builtin_amdgcn_s_setprio(1);
          #pragma unroll
          for (int nf = 0; nf < 4; ++nf){
            const char* vr = vB + (size_t)(w * 64 + nf * 16 + lr) * 128;
            #pragma unroll
            for (int ks = 0; ks < 2; ++ks){
              bf16x8 vb = *(const bf16x8*)(vr + ((ks * 64 + lk16) ^ swz));
              acc[vp][0][nf] = mfma16(pa[0][ks], vb, acc[vp][0][nf]);
              acc[vp][1][nf] = mfma16(pa[1][ks], vb, acc[vp][1][nf]);
            }
          }
          __builtin_amdgcn_s_setprio(0);
        }
        __syncthreads();
        ISSUE_CHUNK(c + 2);
        ++c;
      }
    }

    // ---- epilogue: O / l ----
    {
      float* ob = out + ((size_t)b * SEQ + (size_t)qt * 32) * DIM;
      #pragma unroll
      for (int m = 0; m < 2; ++m)
        #pragma unroll
        for (int r = 0; r < 4; ++r){
          int row = m * 16 + lk * 4 + r;
          float inv = 1.0f / lS[row];
          #pragma unroll
          for (int vp = 0; vp < 2; ++vp)
            #pragma unroll
            for (int nf = 0; nf < 4; ++nf){
              int col = vp * 512 + w * 64 + nf * 16 + lr;
              ob[(size_t)row * DIM + col] = acc[vp][m][nf][r] * inv;
            }
        }
    }
  }
}

// ---------------- launch ----------------
extern "C" void kernel_launch(void* const* d_in, const int* in_sizes, int n_in,
                              void* d_out, int out_size, void* d_ws, size_t ws_size,
                              hipStream_t stream)
{
  (void)in_sizes; (void)n_in; (void)out_size; (void)ws_size;
  const float* emb = (const float*)d_in[0];
  const float* Wq  = (const float*)d_in[1];
  const float* Wk  = (const float*)d_in[2];
  const float* Wv  = (const float*)d_in[3];

  char* ws = (char*)d_ws;
  unsigned short* EB = (unsigned short*)ws;                    // 32MB (later reused as VT)
  unsigned short* WB = (unsigned short*)(ws + 33554432);       // 6MB
  unsigned short* Qb = (unsigned short*)(ws + 39845888);       // 32MB
  unsigned short* Kb = (unsigned short*)(ws + 73400320);       // 32MB
  unsigned short* Vb = (unsigned short*)d_out;                 // V scratch in out buffer
  unsigned short* VT = EB;

  cvt_kernel<<<16384, 256, 0, stream>>>(emb, EB, 4194304);
  cvt_kernel<<<1024, 256, 0, stream>>>(Wq, WB,           262144);
  cvt_kernel<<<1024, 256, 0, stream>>>(Wk, WB + 1048576, 262144);
  cvt_kernel<<<1024, 256, 0, stream>>>(Wv, WB + 2097152, 262144);

  gemm_qkv<<<dim3(8, 128, 3), 256, 0, stream>>>(EB, WB, Qb, Kb, Vb);
  transpose_v<<<dim3(64, 16, 4), 256, 0, stream>>>(Vb, VT);
  flash_attn<<<256, 512, 0, stream>>>(Qb, Kb, VT, (float*)d_out);
}

// Round 5
// 1284.893 us; speedup vs baseline: 1.0373x; 1.0373x over previous
//
#include <hip/hip_runtime.h>
#include <math.h>
#include <stdint.h>

#define SEQ 4096
#define DIM 1024
#define NB  4

typedef __attribute__((ext_vector_type(8))) __bf16 bf16x8;
typedef __attribute__((ext_vector_type(4))) float  f32x4;
typedef __attribute__((ext_vector_type(4))) float  floatx4;
typedef __attribute__((ext_vector_type(8))) unsigned short ushortx8;
typedef __attribute__((ext_vector_type(4))) unsigned short ushortx4;

__device__ __forceinline__ unsigned short f2bf(float f){
  union { float f; unsigned int u; } c; c.f = f;
  unsigned int u = c.u;
  return (unsigned short)((u + 0x7fffu + ((u >> 16) & 1u)) >> 16);
}

__device__ __forceinline__ f32x4 mfma16(bf16x8 a, bf16x8 b, f32x4 c){
  return __builtin_amdgcn_mfma_f32_16x16x32_bf16(a, b, c, 0, 0, 0);
}

__device__ __forceinline__ void g2l16(void* lds, const void* g){
  __builtin_amdgcn_global_load_lds(
      (const __attribute__((address_space(1))) unsigned int*)g,
      (__attribute__((address_space(3))) unsigned int*)lds, 16, 0, 0);
}

#define WAITVM8 asm volatile("s_waitcnt vmcnt(8)" ::: "memory")
#define WAITVM0 asm volatile("s_waitcnt vmcnt(0)" ::: "memory")

// ---------------- fp32 -> bf16 conversion ----------------
__global__ void cvt_kernel(const float* __restrict__ src,
                           unsigned short* __restrict__ dst, int n4){
  int i = blockIdx.x * blockDim.x + threadIdx.x;
  if (i >= n4) return;
  floatx4 v = *((const floatx4*)src + i);
  ushortx4 o;
  o[0] = f2bf(v[0]); o[1] = f2bf(v[1]); o[2] = f2bf(v[2]); o[3] = f2bf(v[3]);
  *((ushortx4*)dst + i) = o;
}

// ---------------- QKV projection GEMM (m97 structure) ----------------
__global__ __launch_bounds__(256, 2) void gemm_qkv(
    const unsigned short* __restrict__ E,
    const unsigned short* __restrict__ W3,
    unsigned short* __restrict__ Qd,
    unsigned short* __restrict__ Kd,
    unsigned short* __restrict__ Vd)
{
  __shared__ unsigned short As[128][64];
  __shared__ unsigned short Bs[128][64];

  const int t  = threadIdx.x;
  const int m0 = blockIdx.y * 128;
  const int n0 = blockIdx.x * 128;
  const unsigned short* W = W3 + (size_t)blockIdx.z * (DIM * (size_t)DIM);
  unsigned short* dst = blockIdx.z == 0 ? Qd : (blockIdx.z == 1 ? Kd : Vd);

  const int l  = t & 63;
  const int w  = t >> 6;
  const int lr = l & 15;
  const int lk = l >> 4;
  const int wr = (w >> 1) * 64;
  const int wc = (w & 1) * 64;

  f32x4 acc[4][4];
  #pragma unroll
  for (int i = 0; i < 4; ++i)
    #pragma unroll
    for (int j = 0; j < 4; ++j) acc[i][j] = (f32x4)0.0f;

  for (int kt = 0; kt < DIM / 64; ++kt){
    const int k0 = kt * 64;
    #pragma unroll
    for (int c = 0; c < 4; ++c){
      int id  = c * 256 + t;
      int row = id >> 3;
      int cb  = (id & 7) * 8;
      g2l16(&As[row][cb], E + (size_t)(m0 + row) * DIM + k0 + cb);
      g2l16(&Bs[row][cb], W + (size_t)(n0 + row) * DIM + k0 + cb);
    }
    asm volatile("s_waitcnt vmcnt(0)" ::: "memory");
    __syncthreads();
    #pragma unroll
    for (int ks = 0; ks < 2; ++ks){
      bf16x8 af[4], bfr[4];
      #pragma unroll
      for (int i = 0; i < 4; ++i){
        af[i]  = *(const bf16x8*)&As[wr + i*16 + lr][ks*32 + lk*8];
        bfr[i] = *(const bf16x8*)&Bs[wc + i*16 + lr][ks*32 + lk*8];
      }
      #pragma unroll
      for (int i = 0; i < 4; ++i)
        #pragma unroll
        for (int j = 0; j < 4; ++j)
          acc[i][j] = mfma16(af[i], bfr[j], acc[i][j]);
    }
    __syncthreads();
  }
  #pragma unroll
  for (int i = 0; i < 4; ++i)
    #pragma unroll
    for (int j = 0; j < 4; ++j)
      #pragma unroll
      for (int r = 0; r < 4; ++r){
        int row = wr + i*16 + lk*4 + r;
        int col = wc + j*16 + lr;
        dst[(size_t)(m0 + row) * DIM + n0 + col] = f2bf(acc[i][j][r]);
      }
}

// ---------------- V transpose ----------------
__global__ __launch_bounds__(256) void transpose_v(
    const unsigned short* __restrict__ V, unsigned short* __restrict__ VT)
{
  __shared__ unsigned short T[64][72];
  const int b  = blockIdx.z;
  const int s0 = blockIdx.x * 64;
  const int a0 = blockIdx.y * 64;
  const unsigned short* Vb = V + (size_t)b * SEQ * DIM;
  unsigned short* VTb = VT + (size_t)b * DIM * SEQ;
  const int t = threadIdx.x;
  const int r = t >> 3, cg = t & 7;
  #pragma unroll
  for (int p = 0; p < 2; ++p){
    int row = r + p * 32;
    ushortx8 v = *(const ushortx8*)(Vb + (size_t)(s0 + row) * DIM + a0 + cg*8);
    *(ushortx8*)&T[row][cg*8] = v;
  }
  __syncthreads();
  #pragma unroll
  for (int p = 0; p < 2; ++p){
    int ar = r + p * 32;
    ushortx8 o;
    #pragma unroll
    for (int j = 0; j < 8; ++j) o[j] = T[cg*8 + j][ar];
    *(ushortx8*)(VTb + (size_t)(a0 + ar) * SEQ + s0 + cg*8) = o;
  }
}

// ---------------- flash attention v5: K-split Q-in-regs (64 VGPR), ds_add S-reduce ----
// BQ=32, BK=64. 256 blocks x 512 threads (8 waves). Tiles (127-pair, pair).
// Per KV iter: 4 phases (K kv-halves 32x1024; V d-halves 512x64), 64KB each,
// ping-pong, 2-ahead, counted vmcnt(8).
// Phase A: wave (n2 = kv-16-group, h = K-quarter) holds Q[32 rows][h*256..+256)
// in 64 VGPR; computes partial S(32x16) over its quarter; ds_add_f32 into Ss.
// Softmax reads summed Ss and re-zeroes it for the next iteration.

// chunk cc: phase p = cc&3 (0,1 = K kv-halves; 2,3 = V d-halves), j = cc>>2
#define ISSUE_CHUNK(cc) do { \
  int _c = (cc); \
  if (_c < nj4){ \
    int _j = _c >> 2, _p = _c & 3; \
    char* _buf = cbuf + (size_t)(_c & 1) * 65536; \
    if (_p < 2){ \
      _Pragma("unroll") \
      for (int _u = 0; _u < 8; ++_u){ \
        int _s = _u * 512 + t; \
        int _r = _s >> 7; \
        int _o = ((_s & 127) * 16) ^ ((_r & 7) << 4); \
        g2l16(_buf + (size_t)_s * 16, \
              (const char*)Kg + (size_t)(_j * 64 + _p * 32 + _r) * 2048 + _o); \
      } \
    } else { \
      _Pragma("unroll") \
      for (int _u = 0; _u < 8; ++_u){ \
        int _s = _u * 512 + t; \
        int _r = _s >> 3; \
        int _o = ((_s & 7) * 16) ^ ((_r & 7) << 4); \
        g2l16(_buf + (size_t)_s * 16, \
              (const char*)VTg + ((size_t)((_p - 2) * 512 + _r) * SEQ + _j * 64) * 2 + _o); \
      } \
    } \
  } \
} while (0)

__global__ __launch_bounds__(512, 2) void flash_attn(
    const unsigned short* __restrict__ Q,
    const unsigned short* __restrict__ K,
    const unsigned short* __restrict__ VT,
    float* __restrict__ out)
{
  __shared__ char cbufRaw[131072];  // 2 x 64KB ping-pong
  __shared__ float Ss[32][68];      // S partial-sum accumulator (zeroed)
  __shared__ unsigned short Ps[32][72];
  __shared__ float mS[32], lS[32], aS[32];

  char* cbuf = cbufRaw;

  const int fid  = blockIdx.x;
  const int xcd  = fid & 7;
  const int b    = xcd >> 1;                      // 2 XCDs per batch
  const int pair = (fid >> 3) + (xcd & 1) * 32;   // 0..63

  const int t  = threadIdx.x;
  const int w  = t >> 6;
  const int l  = t & 63;
  const int lr = l & 15;
  const int lk = l >> 4;
  const int lk16 = lk * 16;
  const int swz  = (lr & 7) << 4;

  const unsigned short* Kg  = K  + (size_t)b * SEQ * DIM;
  const unsigned short* VTg = VT + (size_t)b * DIM * SEQ;

  const float scale = 0.03125f;  // 1/sqrt(1024)

  // phase A roles: wave = (n2, h). 32 rows x 16 kv-cols, K-quarter h.
  const int n2 = w >> 2;
  const int h  = w & 3;

  bf16x8 q[2][8];        // Q[m*16+lr][h*256 + ks*32 + lk*8] : 64 VGPR
  f32x4 acc[2][2][4];    // [vphase][m][nf] : 64 VGPR

  // zero the S accumulator once (stays zeroed across iters/tiles)
  {
    float* sf = &Ss[0][0];
    for (int i = t; i < 32 * 68; i += 512) sf[i] = 0.0f;
  }

  for (int tix = 0; tix < 2; ++tix){
    const int qt = tix ? pair : (127 - pair);
    const int nj = qt / 2 + 1;
    const int nj4 = nj * 4;

    if (tix) __syncthreads();               // epilogue reads / cbuf drain done
    if (t < 32){ mS[t] = -INFINITY; lS[t] = 0.0f; }

    // load wave's Q K-quarter into registers (16 x 16B global loads)
    {
      const unsigned short* Qr =
          Q + ((size_t)b * SEQ + (size_t)qt * 32 + lr) * DIM + h * 256 + lk * 8;
      #pragma unroll
      for (int m = 0; m < 2; ++m)
        #pragma unroll
        for (int ks = 0; ks < 8; ++ks)
          q[m][ks] = *(const bf16x8*)(Qr + (size_t)m * 16 * DIM + ks * 32);
    }
    ISSUE_CHUNK(0);
    ISSUE_CHUNK(1);

    #pragma unroll
    for (int vp = 0; vp < 2; ++vp)
      #pragma unroll
      for (int m = 0; m < 2; ++m)
        #pragma unroll
        for (int nf = 0; nf < 4; ++nf) acc[vp][m][nf] = (f32x4)0.0f;

    int c = 0;
    for (int j = 0; j < nj; ++j){
      // ---- K phases: partial S over this wave's K-quarter, ds_add reduce ----
      #pragma unroll
      for (int jc = 0; jc < 2; ++jc){
        if (c + 1 < nj4) { WAITVM8; } else { WAITVM0; }
        __syncthreads();
        {
          const char* kB = cbuf + (size_t)(c & 1) * 65536
                               + (size_t)(n2 * 16 + lr) * 2048;
          bf16x8 kf[8];
          #pragma unroll
          for (int ks = 0; ks < 8; ++ks)
            kf[ks] = *(const bf16x8*)(kB + ((h * 512 + ks * 64 + lk16) ^ swz));
          f32x4 sa0 = (f32x4)0.0f, sa1 = (f32x4)0.0f;
          __builtin_amdgcn_s_setprio(1);
          #pragma unroll
          for (int ks = 0; ks < 8; ++ks){
            sa0 = mfma16(q[0][ks], kf[ks], sa0);
            sa1 = mfma16(q[1][ks], kf[ks], sa1);
          }
          __builtin_amdgcn_s_setprio(0);
          const int scol = jc * 32 + n2 * 16 + lr;
          #pragma unroll
          for (int r = 0; r < 4; ++r){
            atomicAdd(&Ss[lk * 4 + r][scol],      sa0[r]);
            atomicAdd(&Ss[16 + lk * 4 + r][scol], sa1[r]);
          }
        }
        __syncthreads();
        ISSUE_CHUNK(c + 2);
        ++c;
      }

      // ---- softmax over 32x64 tile; re-zero Ss for next iter ----
      {
        const int row = t >> 4;
        const int cg  = t & 15;
        f32x4 v0 = *(const f32x4*)&Ss[row][cg * 4];
        *(f32x4*)&Ss[row][cg * 4] = (f32x4)0.0f;
        const int grow = qt * 32 + row;
        const int gc0  = j * 64 + cg * 4;
        float svv[4];
        #pragma unroll
        for (int i2 = 0; i2 < 4; ++i2)
          svv[i2] = (gc0 + i2 > grow) ? -INFINITY : v0[i2] * scale;
        float mx = fmaxf(fmaxf(svv[0], svv[1]), fmaxf(svv[2], svv[3]));
        #pragma unroll
        for (int d = 1; d < 16; d <<= 1) mx = fmaxf(mx, __shfl_xor(mx, d, 64));
        float mprev = mS[row];
        float mnew  = fmaxf(mprev, mx);
        float alpha = __expf(mprev - mnew);
        float sum = 0.f;
        ushortx4 pb;
        #pragma unroll
        for (int i2 = 0; i2 < 4; ++i2){
          float p = __expf(svv[i2] - mnew);
          sum += p;
          pb[i2] = f2bf(p);
        }
        #pragma unroll
        for (int d = 1; d < 16; d <<= 1) sum += __shfl_xor(sum, d, 64);
        if (cg == 0){
          mS[row] = mnew;
          lS[row] = lS[row] * alpha + sum;
          aS[row] = alpha;
        }
        *(ushortx4*)&Ps[row][cg * 4] = pb;
      }

      // ---- V phases: O[:, vp*512..] accum; wave = 32 rows x 64 d-cols ----
      #pragma unroll
      for (int vp = 0; vp < 2; ++vp){
        if (c + 1 < nj4) { WAITVM8; } else { WAITVM0; }
        __syncthreads();
        if (vp == 0){
          float al[2][4];
          #pragma unroll
          for (int m = 0; m < 2; ++m)
            #pragma unroll
            for (int r = 0; r < 4; ++r) al[m][r] = aS[m * 16 + lk * 4 + r];
          #pragma unroll
          for (int p2 = 0; p2 < 2; ++p2)
            #pragma unroll
            for (int m = 0; m < 2; ++m)
              #pragma unroll
              for (int nf = 0; nf < 4; ++nf)
                #pragma unroll
                for (int r = 0; r < 4; ++r) acc[p2][m][nf][r] *= al[m][r];
        }
        {
          const char* vB = cbuf + (size_t)(c & 1) * 65536;
          bf16x8 pa[2][2];
          #pragma unroll
          for (int m = 0; m < 2; ++m)
            #pragma unroll
            for (int ks = 0; ks < 2; ++ks)
              pa[m][ks] = *(const bf16x8*)&Ps[m * 16 + lr][ks * 32 + lk * 8];
          __builtin_amdgcn_s_setprio(1);
          #pragma unroll
          for (int nf = 0; nf < 4; ++nf){
            const char* vr = vB + (size_t)(w * 64 + nf * 16 + lr) * 128;
            #pragma unroll
            for (int ks = 0; ks < 2; ++ks){
              bf16x8 vb = *(const bf16x8*)(vr + ((ks * 64 + lk16) ^ swz));
              acc[vp][0][nf] = mfma16(pa[0][ks], vb, acc[vp][0][nf]);
              acc[vp][1][nf] = mfma16(pa[1][ks], vb, acc[vp][1][nf]);
            }
          }
          __builtin_amdgcn_s_setprio(0);
        }
        __syncthreads();
        ISSUE_CHUNK(c + 2);
        ++c;
      }
    }

    // ---- epilogue: O / l ----
    {
      float* ob = out + ((size_t)b * SEQ + (size_t)qt * 32) * DIM;
      #pragma unroll
      for (int m = 0; m < 2; ++m)
        #pragma unroll
        for (int r = 0; r < 4; ++r){
          int row = m * 16 + lk * 4 + r;
          float inv = 1.0f / lS[row];
          #pragma unroll
          for (int vp = 0; vp < 2; ++vp)
            #pragma unroll
            for (int nf = 0; nf < 4; ++nf){
              int col = vp * 512 + w * 64 + nf * 16 + lr;
              ob[(size_t)row * DIM + col] = acc[vp][m][nf][r] * inv;
            }
        }
    }
  }
}

// ---------------- launch ----------------
extern "C" void kernel_launch(void* const* d_in, const int* in_sizes, int n_in,
                              void* d_out, int out_size, void* d_ws, size_t ws_size,
                              hipStream_t stream)
{
  (void)in_sizes; (void)n_in; (void)out_size; (void)ws_size;
  const float* emb = (const float*)d_in[0];
  const float* Wq  = (const float*)d_in[1];
  const float* Wk  = (const float*)d_in[2];
  const float* Wv  = (const float*)d_in[3];

  char* ws = (char*)d_ws;
  unsigned short* EB = (unsigned short*)ws;                    // 32MB (later reused as VT)
  unsigned short* WB = (unsigned short*)(ws + 33554432);       // 6MB
  unsigned short* Qb = (unsigned short*)(ws + 39845888);       // 32MB
  unsigned short* Kb = (unsigned short*)(ws + 73400320);       // 32MB
  unsigned short* Vb = (unsigned short*)d_out;                 // V scratch in out buffer
  unsigned short* VT = EB;

  cvt_kernel<<<16384, 256, 0, stream>>>(emb, EB, 4194304);
  cvt_kernel<<<1024, 256, 0, stream>>>(Wq, WB,           262144);
  cvt_kernel<<<1024, 256, 0, stream>>>(Wk, WB + 1048576, 262144);
  cvt_kernel<<<1024, 256, 0, stream>>>(Wv, WB + 2097152, 262144);

  gemm_qkv<<<dim3(8, 128, 3), 256, 0, stream>>>(EB, WB, Qb, Kb, Vb);
  transpose_v<<<dim3(64, 16, 4), 256, 0, stream>>>(Vb, VT);
  flash_attn<<<256, 512, 0, stream>>>(Qb, Kb, VT, (float*)d_out);
}

// Round 6
// 1284.502 us; speedup vs baseline: 1.0377x; 1.0003x over previous
//
#include <hip/hip_runtime.h>
#include <math.h>
#include <stdint.h>

#define SEQ 4096
#define DIM 1024
#define NB  4

typedef __attribute__((ext_vector_type(8))) __bf16 bf16x8;
typedef __attribute__((ext_vector_type(4))) float  f32x4;
typedef __attribute__((ext_vector_type(4))) float  floatx4;
typedef __attribute__((ext_vector_type(8))) unsigned short ushortx8;
typedef __attribute__((ext_vector_type(4))) unsigned short ushortx4;

__device__ __forceinline__ unsigned short f2bf(float f){
  union { float f; unsigned int u; } c; c.f = f;
  unsigned int u = c.u;
  return (unsigned short)((u + 0x7fffu + ((u >> 16) & 1u)) >> 16);
}

__device__ __forceinline__ f32x4 mfma16(bf16x8 a, bf16x8 b, f32x4 c){
  return __builtin_amdgcn_mfma_f32_16x16x32_bf16(a, b, c, 0, 0, 0);
}

__device__ __forceinline__ void g2l16(void* lds, const void* g){
  __builtin_amdgcn_global_load_lds(
      (const __attribute__((address_space(1))) unsigned int*)g,
      (__attribute__((address_space(3))) unsigned int*)lds, 16, 0, 0);
}

#define WAITVM8 asm volatile("s_waitcnt vmcnt(8)" ::: "memory")
#define WAITVM0 asm volatile("s_waitcnt vmcnt(0)" ::: "memory")

// ---------------- fp32 -> bf16 conversion ----------------
__global__ void cvt_kernel(const float* __restrict__ src,
                           unsigned short* __restrict__ dst, int n4){
  int i = blockIdx.x * blockDim.x + threadIdx.x;
  if (i >= n4) return;
  floatx4 v = *((const floatx4*)src + i);
  ushortx4 o;
  o[0] = f2bf(v[0]); o[1] = f2bf(v[1]); o[2] = f2bf(v[2]); o[3] = f2bf(v[3]);
  *((ushortx4*)dst + i) = o;
}

// ---------------- QKV projection GEMM (m97 structure) ----------------
__global__ __launch_bounds__(256, 2) void gemm_qkv(
    const unsigned short* __restrict__ E,
    const unsigned short* __restrict__ W3,
    unsigned short* __restrict__ Qd,
    unsigned short* __restrict__ Kd,
    unsigned short* __restrict__ Vd)
{
  __shared__ unsigned short As[128][64];
  __shared__ unsigned short Bs[128][64];

  const int t  = threadIdx.x;
  const int m0 = blockIdx.y * 128;
  const int n0 = blockIdx.x * 128;
  const unsigned short* W = W3 + (size_t)blockIdx.z * (DIM * (size_t)DIM);
  unsigned short* dst = blockIdx.z == 0 ? Qd : (blockIdx.z == 1 ? Kd : Vd);

  const int l  = t & 63;
  const int w  = t >> 6;
  const int lr = l & 15;
  const int lk = l >> 4;
  const int wr = (w >> 1) * 64;
  const int wc = (w & 1) * 64;

  f32x4 acc[4][4];
  #pragma unroll
  for (int i = 0; i < 4; ++i)
    #pragma unroll
    for (int j = 0; j < 4; ++j) acc[i][j] = (f32x4)0.0f;

  for (int kt = 0; kt < DIM / 64; ++kt){
    const int k0 = kt * 64;
    #pragma unroll
    for (int c = 0; c < 4; ++c){
      int id  = c * 256 + t;
      int row = id >> 3;
      int cb  = (id & 7) * 8;
      g2l16(&As[row][cb], E + (size_t)(m0 + row) * DIM + k0 + cb);
      g2l16(&Bs[row][cb], W + (size_t)(n0 + row) * DIM + k0 + cb);
    }
    asm volatile("s_waitcnt vmcnt(0)" ::: "memory");
    __syncthreads();
    #pragma unroll
    for (int ks = 0; ks < 2; ++ks){
      bf16x8 af[4], bfr[4];
      #pragma unroll
      for (int i = 0; i < 4; ++i){
        af[i]  = *(const bf16x8*)&As[wr + i*16 + lr][ks*32 + lk*8];
        bfr[i] = *(const bf16x8*)&Bs[wc + i*16 + lr][ks*32 + lk*8];
      }
      #pragma unroll
      for (int i = 0; i < 4; ++i)
        #pragma unroll
        for (int j = 0; j < 4; ++j)
          acc[i][j] = mfma16(af[i], bfr[j], acc[i][j]);
    }
    __syncthreads();
  }
  #pragma unroll
  for (int i = 0; i < 4; ++i)
    #pragma unroll
    for (int j = 0; j < 4; ++j)
      #pragma unroll
      for (int r = 0; r < 4; ++r){
        int row = wr + i*16 + lk*4 + r;
        int col = wc + j*16 + lr;
        dst[(size_t)(m0 + row) * DIM + n0 + col] = f2bf(acc[i][j][r]);
      }
}

// ---------------- V transpose ----------------
__global__ __launch_bounds__(256) void transpose_v(
    const unsigned short* __restrict__ V, unsigned short* __restrict__ VT)
{
  __shared__ unsigned short T[64][72];
  const int b  = blockIdx.z;
  const int s0 = blockIdx.x * 64;
  const int a0 = blockIdx.y * 64;
  const unsigned short* Vb = V + (size_t)b * SEQ * DIM;
  unsigned short* VTb = VT + (size_t)b * DIM * SEQ;
  const int t = threadIdx.x;
  const int r = t >> 3, cg = t & 7;
  #pragma unroll
  for (int p = 0; p < 2; ++p){
    int row = r + p * 32;
    ushortx8 v = *(const ushortx8*)(Vb + (size_t)(s0 + row) * DIM + a0 + cg*8);
    *(ushortx8*)&T[row][cg*8] = v;
  }
  __syncthreads();
  #pragma unroll
  for (int p = 0; p < 2; ++p){
    int ar = r + p * 32;
    ushortx8 o;
    #pragma unroll
    for (int j = 0; j < 8; ++j) o[j] = T[cg*8 + j][ar];
    *(ushortx8*)(VTb + (size_t)(a0 + ar) * SEQ + s0 + cg*8) = o;
  }
}

// ---------------- flash attention v6: v5 structure + launch_bounds(512,1) ----------------
// BQ=32, BK=64. 256 blocks x 512 threads (8 waves). Tiles (127-pair, pair).
// Per KV iter: 4 phases (K kv-halves 32x1024; V d-halves 512x64), 64KB each,
// ping-pong, 2-ahead, counted vmcnt(8).
// Phase A: wave (n2 = kv-16-group, h = K-quarter) holds Q[32 rows][h*256..+256)
// in 64 VGPR; partial S(32x16) over its quarter; ds_add_f32 reduce into Ss.

// chunk cc: phase p = cc&3 (0,1 = K kv-halves; 2,3 = V d-halves), j = cc>>2
#define ISSUE_CHUNK(cc) do { \
  int _c = (cc); \
  if (_c < nj4){ \
    int _j = _c >> 2, _p = _c & 3; \
    char* _buf = cbuf + (size_t)(_c & 1) * 65536; \
    if (_p < 2){ \
      _Pragma("unroll") \
      for (int _u = 0; _u < 8; ++_u){ \
        int _s = _u * 512 + t; \
        int _r = _s >> 7; \
        int _o = ((_s & 127) * 16) ^ ((_r & 7) << 4); \
        g2l16(_buf + (size_t)_s * 16, \
              (const char*)Kg + (size_t)(_j * 64 + _p * 32 + _r) * 2048 + _o); \
      } \
    } else { \
      _Pragma("unroll") \
      for (int _u = 0; _u < 8; ++_u){ \
        int _s = _u * 512 + t; \
        int _r = _s >> 3; \
        int _o = ((_s & 7) * 16) ^ ((_r & 7) << 4); \
        g2l16(_buf + (size_t)_s * 16, \
              (const char*)VTg + ((size_t)((_p - 2) * 512 + _r) * SEQ + _j * 64) * 2 + _o); \
      } \
    } \
  } \
} while (0)

__global__ __launch_bounds__(512, 1) void flash_attn(
    const unsigned short* __restrict__ Q,
    const unsigned short* __restrict__ K,
    const unsigned short* __restrict__ VT,
    float* __restrict__ out)
{
  __shared__ char cbufRaw[131072];  // 2 x 64KB ping-pong
  __shared__ float Ss[32][68];      // S partial-sum accumulator (zeroed)
  __shared__ unsigned short Ps[32][72];
  __shared__ float mS[32], lS[32], aS[32];

  char* cbuf = cbufRaw;

  const int fid  = blockIdx.x;
  const int xcd  = fid & 7;
  const int b    = xcd >> 1;                      // 2 XCDs per batch
  const int pair = (fid >> 3) + (xcd & 1) * 32;   // 0..63

  const int t  = threadIdx.x;
  const int w  = t >> 6;
  const int l  = t & 63;
  const int lr = l & 15;
  const int lk = l >> 4;
  const int lk16 = lk * 16;
  const int swz  = (lr & 7) << 4;

  const unsigned short* Kg  = K  + (size_t)b * SEQ * DIM;
  const unsigned short* VTg = VT + (size_t)b * DIM * SEQ;

  const float scale = 0.03125f;  // 1/sqrt(1024)

  // phase A roles: wave = (n2, h). 32 rows x 16 kv-cols, K-quarter h.
  const int n2 = w >> 2;
  const int h  = w & 3;

  bf16x8 q[2][8];        // Q[m*16+lr][h*256 + ks*32 + lk*8] : 64 VGPR
  f32x4 acc[2][2][4];    // [vphase][m][nf] : 64 VGPR

  // zero the S accumulator once (stays zeroed across iters/tiles)
  {
    float* sf = &Ss[0][0];
    for (int i = t; i < 32 * 68; i += 512) sf[i] = 0.0f;
  }

  for (int tix = 0; tix < 2; ++tix){
    const int qt = tix ? pair : (127 - pair);
    const int nj = qt / 2 + 1;
    const int nj4 = nj * 4;

    if (tix) __syncthreads();               // epilogue reads / cbuf drain done
    if (t < 32){ mS[t] = -INFINITY; lS[t] = 0.0f; }

    // load wave's Q K-quarter into registers (16 x 16B global loads)
    {
      const unsigned short* Qr =
          Q + ((size_t)b * SEQ + (size_t)qt * 32 + lr) * DIM + h * 256 + lk * 8;
      #pragma unroll
      for (int m = 0; m < 2; ++m)
        #pragma unroll
        for (int ks = 0; ks < 8; ++ks)
          q[m][ks] = *(const bf16x8*)(Qr + (size_t)m * 16 * DIM + ks * 32);
    }
    ISSUE_CHUNK(0);
    ISSUE_CHUNK(1);

    #pragma unroll
    for (int vp = 0; vp < 2; ++vp)
      #pragma unroll
      for (int m = 0; m < 2; ++m)
        #pragma unroll
        for (int nf = 0; nf < 4; ++nf) acc[vp][m][nf] = (f32x4)0.0f;

    int c = 0;
    for (int j = 0; j < nj; ++j){
      // ---- K phases: partial S over this wave's K-quarter, ds_add reduce ----
      #pragma unroll
      for (int jc = 0; jc < 2; ++jc){
        if (c + 1 < nj4) { WAITVM8; } else { WAITVM0; }
        __syncthreads();
        {
          const char* kB = cbuf + (size_t)(c & 1) * 65536
                               + (size_t)(n2 * 16 + lr) * 2048;
          bf16x8 kf[8];
          #pragma unroll
          for (int ks = 0; ks < 8; ++ks)
            kf[ks] = *(const bf16x8*)(kB + ((h * 512 + ks * 64 + lk16) ^ swz));
          f32x4 sa0 = (f32x4)0.0f, sa1 = (f32x4)0.0f;
          __builtin_amdgcn_s_setprio(1);
          #pragma unroll
          for (int ks = 0; ks < 8; ++ks){
            sa0 = mfma16(q[0][ks], kf[ks], sa0);
            sa1 = mfma16(q[1][ks], kf[ks], sa1);
          }
          __builtin_amdgcn_s_setprio(0);
          const int scol = jc * 32 + n2 * 16 + lr;
          #pragma unroll
          for (int r = 0; r < 4; ++r){
            atomicAdd(&Ss[lk * 4 + r][scol],      sa0[r]);
            atomicAdd(&Ss[16 + lk * 4 + r][scol], sa1[r]);
          }
        }
        __syncthreads();
        ISSUE_CHUNK(c + 2);
        ++c;
      }

      // ---- softmax over 32x64 tile; re-zero Ss for next iter ----
      {
        const int row = t >> 4;
        const int cg  = t & 15;
        f32x4 v0 = *(const f32x4*)&Ss[row][cg * 4];
        *(f32x4*)&Ss[row][cg * 4] = (f32x4)0.0f;
        const int grow = qt * 32 + row;
        const int gc0  = j * 64 + cg * 4;
        float svv[4];
        #pragma unroll
        for (int i2 = 0; i2 < 4; ++i2)
          svv[i2] = (gc0 + i2 > grow) ? -INFINITY : v0[i2] * scale;
        float mx = fmaxf(fmaxf(svv[0], svv[1]), fmaxf(svv[2], svv[3]));
        #pragma unroll
        for (int d = 1; d < 16; d <<= 1) mx = fmaxf(mx, __shfl_xor(mx, d, 64));
        float mprev = mS[row];
        float mnew  = fmaxf(mprev, mx);
        float alpha = __expf(mprev - mnew);
        float sum = 0.f;
        ushortx4 pb;
        #pragma unroll
        for (int i2 = 0; i2 < 4; ++i2){
          float p = __expf(svv[i2] - mnew);
          sum += p;
          pb[i2] = f2bf(p);
        }
        #pragma unroll
        for (int d = 1; d < 16; d <<= 1) sum += __shfl_xor(sum, d, 64);
        if (cg == 0){
          mS[row] = mnew;
          lS[row] = lS[row] * alpha + sum;
          aS[row] = alpha;
        }
        *(ushortx4*)&Ps[row][cg * 4] = pb;
      }

      // ---- V phases: O[:, vp*512..] accum; wave = 32 rows x 64 d-cols ----
      #pragma unroll
      for (int vp = 0; vp < 2; ++vp){
        if (c + 1 < nj4) { WAITVM8; } else { WAITVM0; }
        __syncthreads();
        if (vp == 0){
          float al[2][4];
          #pragma unroll
          for (int m = 0; m < 2; ++m)
            #pragma unroll
            for (int r = 0; r < 4; ++r) al[m][r] = aS[m * 16 + lk * 4 + r];
          #pragma unroll
          for (int p2 = 0; p2 < 2; ++p2)
            #pragma unroll
            for (int m = 0; m < 2; ++m)
              #pragma unroll
              for (int nf = 0; nf < 4; ++nf)
                #pragma unroll
                for (int r = 0; r < 4; ++r) acc[p2][m][nf][r] *= al[m][r];
        }
        {
          const char* vB = cbuf + (size_t)(c & 1) * 65536;
          bf16x8 pa[2][2];
          #pragma unroll
          for (int m = 0; m < 2; ++m)
            #pragma unroll
            for (int ks = 0; ks < 2; ++ks)
              pa[m][ks] = *(const bf16x8*)&Ps[m * 16 + lr][ks * 32 + lk * 8];
          __builtin_amdgcn_s_setprio(1);
          #pragma unroll
          for (int nf = 0; nf < 4; ++nf){
            const char* vr = vB + (size_t)(w * 64 + nf * 16 + lr) * 128;
            #pragma unroll
            for (int ks = 0; ks < 2; ++ks){
              bf16x8 vb = *(const bf16x8*)(vr + ((ks * 64 + lk16) ^ swz));
              acc[vp][0][nf] = mfma16(pa[0][ks], vb, acc[vp][0][nf]);
              acc[vp][1][nf] = mfma16(pa[1][ks], vb, acc[vp][1][nf]);
            }
          }
          __builtin_amdgcn_s_setprio(0);
        }
        __syncthreads();
        ISSUE_CHUNK(c + 2);
        ++c;
      }
    }

    // ---- epilogue: O / l ----
    {
      float* ob = out + ((size_t)b * SEQ + (size_t)qt * 32) * DIM;
      #pragma unroll
      for (int m = 0; m < 2; ++m)
        #pragma unroll
        for (int r = 0; r < 4; ++r){
          int row = m * 16 + lk * 4 + r;
          float inv = 1.0f / lS[row];
          #pragma unroll
          for (int vp = 0; vp < 2; ++vp)
            #pragma unroll
            for (int nf = 0; nf < 4; ++nf){
              int col = vp * 512 + w * 64 + nf * 16 + lr;
              ob[(size_t)row * DIM + col] = acc[vp][m][nf][r] * inv;
            }
        }
    }
  }
}

// ---------------- launch ----------------
extern "C" void kernel_launch(void* const* d_in, const int* in_sizes, int n_in,
                              void* d_out, int out_size, void* d_ws, size_t ws_size,
                              hipStream_t stream)
{
  (void)in_sizes; (void)n_in; (void)out_size; (void)ws_size;
  const float* emb = (const float*)d_in[0];
  const float* Wq  = (const float*)d_in[1];
  const float* Wk  = (const float*)d_in[2];
  const float* Wv  = (const float*)d_in[3];

  char* ws = (char*)d_ws;
  unsigned short* EB = (unsigned short*)ws;                    // 32MB (later reused as VT)
  unsigned short* WB = (unsigned short*)(ws + 33554432);       // 6MB
  unsigned short* Qb = (unsigned short*)(ws + 39845888);       // 32MB
  unsigned short* Kb = (unsigned short*)(ws + 73400320);       // 32MB
  unsigned short* Vb = (unsigned short*)d_out;                 // V scratch in out buffer
  unsigned short* VT = EB;

  cvt_kernel<<<16384, 256, 0, stream>>>(emb, EB, 4194304);
  cvt_kernel<<<1024, 256, 0, stream>>>(Wq, WB,           262144);
  cvt_kernel<<<1024, 256, 0, stream>>>(Wk, WB + 1048576, 262144);
  cvt_kernel<<<1024, 256, 0, stream>>>(Wv, WB + 2097152, 262144);

  gemm_qkv<<<dim3(8, 128, 3), 256, 0, stream>>>(EB, WB, Qb, Kb, Vb);
  transpose_v<<<dim3(64, 16, 4), 256, 0, stream>>>(Vb, VT);
  flash_attn<<<256, 512, 0, stream>>>(Qb, Kb, VT, (float*)d_out);
}

// Round 7
// 964.864 us; speedup vs baseline: 1.3814x; 1.3313x over previous
//
#include <hip/hip_runtime.h>
#include <math.h>
#include <stdint.h>

#define SEQ 4096
#define DIM 1024
#define NB  4

typedef __attribute__((ext_vector_type(8)))  __bf16 bf16x8;
typedef __attribute__((ext_vector_type(4)))  float  f32x4;
typedef __attribute__((ext_vector_type(16))) float  f32x16;
typedef __attribute__((ext_vector_type(4)))  float  floatx4;
typedef __attribute__((ext_vector_type(8)))  unsigned short ushortx8;
typedef __attribute__((ext_vector_type(4)))  unsigned short ushortx4;

__device__ __forceinline__ unsigned short f2bf(float f){
  union { float f; unsigned int u; } c; c.f = f;
  unsigned int u = c.u;
  return (unsigned short)((u + 0x7fffu + ((u >> 16) & 1u)) >> 16);
}

__device__ __forceinline__ f32x4 mfma16(bf16x8 a, bf16x8 b, f32x4 c){
  return __builtin_amdgcn_mfma_f32_16x16x32_bf16(a, b, c, 0, 0, 0);
}

__device__ __forceinline__ f32x16 mfma32(bf16x8 a, bf16x8 b, f32x16 c){
  return __builtin_amdgcn_mfma_f32_32x32x16_bf16(a, b, c, 0, 0, 0);
}

__device__ __forceinline__ void g2l16(void* lds, const void* g){
  __builtin_amdgcn_global_load_lds(
      (const __attribute__((address_space(1))) unsigned int*)g,
      (__attribute__((address_space(3))) unsigned int*)lds, 16, 0, 0);
}

#define WAITVM4 asm volatile("s_waitcnt vmcnt(4)" ::: "memory")
#define WAITVM0 asm volatile("s_waitcnt vmcnt(0)" ::: "memory")

// ---------------- fp32 -> bf16 conversion ----------------
__global__ void cvt_kernel(const float* __restrict__ src,
                           unsigned short* __restrict__ dst, int n4){
  int i = blockIdx.x * blockDim.x + threadIdx.x;
  if (i >= n4) return;
  floatx4 v = *((const floatx4*)src + i);
  ushortx4 o;
  o[0] = f2bf(v[0]); o[1] = f2bf(v[1]); o[2] = f2bf(v[2]); o[3] = f2bf(v[3]);
  *((ushortx4*)dst + i) = o;
}

// ---------------- QKV projection GEMM (m97 structure) ----------------
__global__ __launch_bounds__(256, 2) void gemm_qkv(
    const unsigned short* __restrict__ E,
    const unsigned short* __restrict__ W3,
    unsigned short* __restrict__ Qd,
    unsigned short* __restrict__ Kd,
    unsigned short* __restrict__ Vd)
{
  __shared__ unsigned short As[128][64];
  __shared__ unsigned short Bs[128][64];

  const int t  = threadIdx.x;
  const int m0 = blockIdx.y * 128;
  const int n0 = blockIdx.x * 128;
  const unsigned short* W = W3 + (size_t)blockIdx.z * (DIM * (size_t)DIM);
  unsigned short* dst = blockIdx.z == 0 ? Qd : (blockIdx.z == 1 ? Kd : Vd);

  const int l  = t & 63;
  const int w  = t >> 6;
  const int lr = l & 15;
  const int lk = l >> 4;
  const int wr = (w >> 1) * 64;
  const int wc = (w & 1) * 64;

  f32x4 acc[4][4];
  #pragma unroll
  for (int i = 0; i < 4; ++i)
    #pragma unroll
    for (int j = 0; j < 4; ++j) acc[i][j] = (f32x4)0.0f;

  for (int kt = 0; kt < DIM / 64; ++kt){
    const int k0 = kt * 64;
    #pragma unroll
    for (int c = 0; c < 4; ++c){
      int id  = c * 256 + t;
      int row = id >> 3;
      int cb  = (id & 7) * 8;
      g2l16(&As[row][cb], E + (size_t)(m0 + row) * DIM + k0 + cb);
      g2l16(&Bs[row][cb], W + (size_t)(n0 + row) * DIM + k0 + cb);
    }
    asm volatile("s_waitcnt vmcnt(0)" ::: "memory");
    __syncthreads();
    #pragma unroll
    for (int ks = 0; ks < 2; ++ks){
      bf16x8 af[4], bfr[4];
      #pragma unroll
      for (int i = 0; i < 4; ++i){
        af[i]  = *(const bf16x8*)&As[wr + i*16 + lr][ks*32 + lk*8];
        bfr[i] = *(const bf16x8*)&Bs[wc + i*16 + lr][ks*32 + lk*8];
      }
      #pragma unroll
      for (int i = 0; i < 4; ++i)
        #pragma unroll
        for (int j = 0; j < 4; ++j)
          acc[i][j] = mfma16(af[i], bfr[j], acc[i][j]);
    }
    __syncthreads();
  }
  #pragma unroll
  for (int i = 0; i < 4; ++i)
    #pragma unroll
    for (int j = 0; j < 4; ++j)
      #pragma unroll
      for (int r = 0; r < 4; ++r){
        int row = wr + i*16 + lk*4 + r;
        int col = wc + j*16 + lr;
        dst[(size_t)(m0 + row) * DIM + n0 + col] = f2bf(acc[i][j][r]);
      }
}

// ---------------- V transpose ----------------
__global__ __launch_bounds__(256) void transpose_v(
    const unsigned short* __restrict__ V, unsigned short* __restrict__ VT)
{
  __shared__ unsigned short T[64][72];
  const int b  = blockIdx.z;
  const int s0 = blockIdx.x * 64;
  const int a0 = blockIdx.y * 64;
  const unsigned short* Vb = V + (size_t)b * SEQ * DIM;
  unsigned short* VTb = VT + (size_t)b * DIM * SEQ;
  const int t = threadIdx.x;
  const int r = t >> 3, cg = t & 7;
  #pragma unroll
  for (int p = 0; p < 2; ++p){
    int row = r + p * 32;
    ushortx8 v = *(const ushortx8*)(Vb + (size_t)(s0 + row) * DIM + a0 + cg*8);
    *(ushortx8*)&T[row][cg*8] = v;
  }
  __syncthreads();
  #pragma unroll
  for (int p = 0; p < 2; ++p){
    int ar = r + p * 32;
    ushortx8 o;
    #pragma unroll
    for (int j = 0; j < 8; ++j) o[j] = T[cg*8 + j][ar];
    *(ushortx8*)(VTb + (size_t)(a0 + ar) * SEQ + s0 + cg*8) = o;
  }
}

// ---------------- flash attention v7: mfma32, BK=128, all-LDS ----------------
// BQ=32, BK=128. 256 blocks x 512 threads (8 waves). Tiles (127-pair, pair).
// Per KV iter: 16 phases of 32KB: 8 K-chunks [128kv][128k] + 8 V-chunks
// [256d][64kv]; ping-pong 2x32KB, 2-ahead, counted vmcnt(4).
// Phase A: wave (nf = kv-frag 0..3, h = k-half) accumulates partial S(32x32)
// in one f32x16 AGPR acc across the 8 K-chunks; one ds_add_f32 set per iter.
// Phase C: wave w = d-frag; acc[4] f32x16 = O[32][w*32 across 4 d-quarters].

// chunk cc: p = cc&15 (0..7 = K k-chunks; 8..15 = V chunks), j = cc>>4
#define ISSUE_CHUNK(cc) do { \
  int _c = (cc); \
  if (_c < nj16){ \
    int _j = _c >> 4, _p = _c & 15; \
    char* _buf = cbuf + (size_t)(_c & 1) * 32768; \
    if (_p < 8){ \
      _Pragma("unroll") \
      for (int _u = 0; _u < 4; ++_u){ \
        int _s = _u * 512 + t; \
        int _r = _s >> 4; \
        int _o = ((_s & 15) * 16) ^ ((_r & 7) << 4); \
        g2l16(_buf + (size_t)_s * 16, \
              (const char*)Kg + (size_t)(_j * 128 + _r) * 2048 + _p * 256 + _o); \
      } \
    } else { \
      int _vc = _p - 8; \
      _Pragma("unroll") \
      for (int _u = 0; _u < 4; ++_u){ \
        int _s = _u * 512 + t; \
        int _r = _s >> 3; \
        int _o = ((_s & 7) * 16) ^ ((_r & 7) << 4); \
        g2l16(_buf + (size_t)_s * 16, \
              (const char*)VTg + (size_t)((_vc & 3) * 256 + _r) * 8192 \
                               + (size_t)_j * 256 + (_vc >> 2) * 128 + _o); \
      } \
    } \
  } \
} while (0)

#define STAGE_Q(qtile) do { \
  const unsigned short* _Qg = Q + ((size_t)b * SEQ + (size_t)(qtile) * 32) * DIM; \
  _Pragma("unroll") \
  for (int _u = 0; _u < 8; ++_u){ \
    int _s = _u * 512 + t; \
    int _row = _s >> 7; \
    int _sB = ((_s & 127) * 16) ^ ((_row & 7) << 4); \
    g2l16(QsB + (size_t)_s * 16, (const char*)_Qg + (size_t)_row * 2048 + _sB); \
  } \
} while (0)

__global__ __launch_bounds__(512, 2) void flash_attn(
    const unsigned short* __restrict__ Q,
    const unsigned short* __restrict__ K,
    const unsigned short* __restrict__ VT,
    float* __restrict__ out)
{
  __shared__ __align__(16) char QsB[65536];        // Q 32x1024 bf16, swizzled
  __shared__ __align__(16) char cbufRaw[65536];    // 2 x 32KB ping-pong
  __shared__ __align__(16) float Ssf[32][132];     // S accumulator (kept zeroed)
  __shared__ __align__(16) unsigned short Ps[32][136];
  __shared__ __align__(16) float mS[32];
  __shared__ __align__(16) float lS[32];
  __shared__ __align__(16) float aS[32];

  char* cbuf = cbufRaw;

  const int fid  = blockIdx.x;
  const int xcd  = fid & 7;
  const int b    = xcd >> 1;                      // 2 XCDs per batch
  const int pair = (fid >> 3) + (xcd & 1) * 32;   // 0..63

  const int t   = threadIdx.x;
  const int w   = t >> 6;
  const int l   = t & 63;
  const int l31 = l & 31;
  const int lh  = l >> 5;          // 0/1: k-subgroup within frag
  const int lh4 = lh * 4;
  const int swz = (l31 & 7) << 4;

  const unsigned short* Kg  = K  + (size_t)b * SEQ * DIM;
  const unsigned short* VTg = VT + (size_t)b * DIM * SEQ;

  const float scale = 0.03125f;  // 1/sqrt(1024)

  // phase A roles: nf = kv-frag (S cols nf*32..+32), h = k-half of each chunk
  const int nf = w & 3;
  const int h  = w >> 2;

  const char* aQ = QsB + (size_t)l31 * 2048;   // Q row base (A-frag rows)

  // zero the S accumulator once (softmax re-zeroes each iter)
  {
    float* sf = &Ssf[0][0];
    for (int i = t; i < 32 * 132; i += 512) sf[i] = 0.0f;
  }

  for (int tix = 0; tix < 2; ++tix){
    const int qt   = tix ? pair : (127 - pair);
    const int nj   = qt / 4 + 1;
    const int nj16 = nj * 16;

    if (tix) __syncthreads();     // tile-0 reads of Qs/cbuf fully done
    if (t < 32){ mS[t] = -INFINITY; lS[t] = 0.0f; }

    STAGE_Q(qt);
    ISSUE_CHUNK(0);
    ISSUE_CHUNK(1);

    f32x16 acc[4];
    #pragma unroll
    for (int dc = 0; dc < 4; ++dc) acc[dc] = (f32x16)0.0f;

    int c = 0;
    for (int j = 0; j < nj; ++j){
      f32x16 spart = (f32x16)0.0f;

      // ---- 8 K-chunk phases: partial S over (nf kv-frag, h k-half) ----
      #pragma unroll
      for (int dc = 0; dc < 8; ++dc){
        if (c + 1 < nj16) { WAITVM4; } else { WAITVM0; }
        __syncthreads();
        {
          const char* kB = cbuf + (size_t)(c & 1) * 32768
                               + (size_t)(nf * 32 + l31) * 256;
          const int abase = dc * 256 + h * 128 + lh * 16;
          const int bbase = h * 128 + lh * 16;
          __builtin_amdgcn_s_setprio(1);
          #pragma unroll
          for (int ks = 0; ks < 4; ++ks){
            bf16x8 a  = *(const bf16x8*)(aQ + ((abase + ks * 32) ^ swz));
            bf16x8 bv = *(const bf16x8*)(kB + ((bbase + ks * 32) ^ swz));
            spart = mfma32(a, bv, spart);
          }
          __builtin_amdgcn_s_setprio(0);
        }
        if (dc == 7){
          #pragma unroll
          for (int g = 0; g < 4; ++g)
            #pragma unroll
            for (int r4 = 0; r4 < 4; ++r4)
              atomicAdd(&Ssf[g * 8 + lh4 + r4][nf * 32 + l31], spart[g * 4 + r4]);
        }
        __syncthreads();
        ISSUE_CHUNK(c + 2);
        ++c;
      }

      // ---- softmax over 32x128 tile; re-zero Ssf (V loads in flight) ----
      {
        const int row = t >> 4;
        const int cg  = t & 15;
        f32x4 v0 = *(const f32x4*)&Ssf[row][cg * 8];
        f32x4 v1 = *(const f32x4*)&Ssf[row][cg * 8 + 4];
        *(f32x4*)&Ssf[row][cg * 8]     = (f32x4)0.0f;
        *(f32x4*)&Ssf[row][cg * 8 + 4] = (f32x4)0.0f;
        const int grow = qt * 32 + row;
        const int gc0  = j * 128 + cg * 8;
        float sv[8];
        #pragma unroll
        for (int i2 = 0; i2 < 4; ++i2){
          sv[i2]     = (gc0 + i2     > grow) ? -INFINITY : v0[i2] * scale;
          sv[i2 + 4] = (gc0 + i2 + 4 > grow) ? -INFINITY : v1[i2] * scale;
        }
        float mx = sv[0];
        #pragma unroll
        for (int i2 = 1; i2 < 8; ++i2) mx = fmaxf(mx, sv[i2]);
        #pragma unroll
        for (int d = 1; d < 16; d <<= 1) mx = fmaxf(mx, __shfl_xor(mx, d, 64));
        float mprev = mS[row];
        float mnew  = fmaxf(mprev, mx);
        float alpha = __expf(mprev - mnew);
        float sum = 0.f;
        ushortx8 pb;
        #pragma unroll
        for (int i2 = 0; i2 < 8; ++i2){
          float p = __expf(sv[i2] - mnew);
          sum += p;
          pb[i2] = f2bf(p);
        }
        #pragma unroll
        for (int d = 1; d < 16; d <<= 1) sum += __shfl_xor(sum, d, 64);
        if (cg == 0){
          mS[row] = mnew;
          lS[row] = lS[row] * alpha + sum;
          aS[row] = alpha;
        }
        *(ushortx8*)&Ps[row][cg * 8] = pb;
      }

      // ---- 8 V-chunk phases: wave w = d-frag; vc = (kv-half<<2)|d-quarter ----
      #pragma unroll
      for (int vc = 0; vc < 8; ++vc){
        if (c + 1 < nj16) { WAITVM4; } else { WAITVM0; }
        __syncthreads();
        if (vc == 0){
          f32x4 al[4];
          #pragma unroll
          for (int g = 0; g < 4; ++g) al[g] = *(const f32x4*)&aS[g * 8 + lh4];
          #pragma unroll
          for (int dc2 = 0; dc2 < 4; ++dc2)
            #pragma unroll
            for (int g = 0; g < 4; ++g)
              #pragma unroll
              for (int r4 = 0; r4 < 4; ++r4)
                acc[dc2][g * 4 + r4] *= al[g][r4];
        }
        {
          const char* vB = cbuf + (size_t)(c & 1) * 32768
                               + (size_t)(w * 32 + l31) * 128;
          const unsigned short* pA = &Ps[l31][(vc >> 2) * 64 + lh * 8];
          __builtin_amdgcn_s_setprio(1);
          #pragma unroll
          for (int ks = 0; ks < 4; ++ks){
            bf16x8 a  = *(const bf16x8*)(pA + ks * 16);
            bf16x8 bv = *(const bf16x8*)(vB + ((ks * 32 + lh * 16) ^ swz));
            acc[vc & 3] = mfma32(a, bv, acc[vc & 3]);
          }
          __builtin_amdgcn_s_setprio(0);
        }
        __syncthreads();
        ISSUE_CHUNK(c + 2);
        ++c;
      }
    }

    // ---- epilogue: O / l ----
    {
      f32x4 lv[4];
      #pragma unroll
      for (int g = 0; g < 4; ++g) lv[g] = *(const f32x4*)&lS[g * 8 + lh4];
      float* ob = out + ((size_t)b * SEQ + (size_t)qt * 32) * DIM + w * 32 + l31;
      #pragma unroll
      for (int g = 0; g < 4; ++g)
        #pragma unroll
        for (int r4 = 0; r4 < 4; ++r4){
          float inv = 1.0f / lv[g][r4];
          int row = g * 8 + lh4 + r4;
          #pragma unroll
          for (int dc2 = 0; dc2 < 4; ++dc2)
            ob[(size_t)row * DIM + dc2 * 256] = acc[dc2][g * 4 + r4] * inv;
        }
    }
  }
}

// ---------------- launch ----------------
extern "C" void kernel_launch(void* const* d_in, const int* in_sizes, int n_in,
                              void* d_out, int out_size, void* d_ws, size_t ws_size,
                              hipStream_t stream)
{
  (void)in_sizes; (void)n_in; (void)out_size; (void)ws_size;
  const float* emb = (const float*)d_in[0];
  const float* Wq  = (const float*)d_in[1];
  const float* Wk  = (const float*)d_in[2];
  const float* Wv  = (const float*)d_in[3];

  char* ws = (char*)d_ws;
  unsigned short* EB = (unsigned short*)ws;                    // 32MB (later reused as VT)
  unsigned short* WB = (unsigned short*)(ws + 33554432);       // 6MB
  unsigned short* Qb = (unsigned short*)(ws + 39845888);       // 32MB
  unsigned short* Kb = (unsigned short*)(ws + 73400320);       // 32MB
  unsigned short* Vb = (unsigned short*)d_out;                 // V scratch in out buffer
  unsigned short* VT = EB;

  cvt_kernel<<<16384, 256, 0, stream>>>(emb, EB, 4194304);
  cvt_kernel<<<1024, 256, 0, stream>>>(Wq, WB,           262144);
  cvt_kernel<<<1024, 256, 0, stream>>>(Wk, WB + 1048576, 262144);
  cvt_kernel<<<1024, 256, 0, stream>>>(Wv, WB + 2097152, 262144);

  gemm_qkv<<<dim3(8, 128, 3), 256, 0, stream>>>(EB, WB, Qb, Kb, Vb);
  transpose_v<<<dim3(64, 16, 4), 256, 0, stream>>>(Vb, VT);
  flash_attn<<<256, 512, 0, stream>>>(Qb, Kb, VT, (float*)d_out);
}

// Round 8
// 435.604 us; speedup vs baseline: 3.0598x; 2.2150x over previous
//
#include <hip/hip_runtime.h>
#include <math.h>
#include <stdint.h>

#define SEQ 4096
#define DIM 1024
#define NB  4
#define NTILE 32              // 4096/128 M-tiles per batch
#define TRI  528              // NTILE*(NTILE+1)/2 packed causal tiles

typedef __attribute__((ext_vector_type(8))) __bf16 bf16x8;
typedef __attribute__((ext_vector_type(4))) float  f32x4;
typedef __attribute__((ext_vector_type(4))) float  floatx4;
typedef __attribute__((ext_vector_type(8))) unsigned short ushortx8;
typedef __attribute__((ext_vector_type(4))) unsigned short ushortx4;

__device__ __forceinline__ unsigned short f2bf(float f){
  union { float f; unsigned int u; } c; c.f = f;
  unsigned int u = c.u;
  return (unsigned short)((u + 0x7fffu + ((u >> 16) & 1u)) >> 16);
}

__device__ __forceinline__ f32x4 mfma16(bf16x8 a, bf16x8 b, f32x4 c){
  return __builtin_amdgcn_mfma_f32_16x16x32_bf16(a, b, c, 0, 0, 0);
}

__device__ __forceinline__ void g2l16(void* lds, const void* g){
  __builtin_amdgcn_global_load_lds(
      (const __attribute__((address_space(1))) unsigned int*)g,
      (__attribute__((address_space(3))) unsigned int*)lds, 16, 0, 0);
}

// ---------------- fp32 -> bf16 conversion ----------------
__global__ void cvt_kernel(const float* __restrict__ src,
                           unsigned short* __restrict__ dst, int n4){
  int i = blockIdx.x * blockDim.x + threadIdx.x;
  if (i >= n4) return;
  floatx4 v = *((const floatx4*)src + i);
  ushortx4 o;
  o[0] = f2bf(v[0]); o[1] = f2bf(v[1]); o[2] = f2bf(v[2]); o[3] = f2bf(v[3]);
  *((ushortx4*)dst + i) = o;
}

// ---------------- QKV projection GEMM (m97 structure) ----------------
__global__ __launch_bounds__(256, 2) void gemm_qkv(
    const unsigned short* __restrict__ E,
    const unsigned short* __restrict__ W3,
    unsigned short* __restrict__ Qd,
    unsigned short* __restrict__ Kd,
    unsigned short* __restrict__ Vd)
{
  __shared__ unsigned short As[128][64];
  __shared__ unsigned short Bs[128][64];

  const int t  = threadIdx.x;
  const int m0 = blockIdx.y * 128;
  const int n0 = blockIdx.x * 128;
  const unsigned short* W = W3 + (size_t)blockIdx.z * (DIM * (size_t)DIM);
  unsigned short* dst = blockIdx.z == 0 ? Qd : (blockIdx.z == 1 ? Kd : Vd);

  const int l  = t & 63;
  const int w  = t >> 6;
  const int lr = l & 15;
  const int lk = l >> 4;
  const int wr = (w >> 1) * 64;
  const int wc = (w & 1) * 64;

  f32x4 acc[4][4];
  #pragma unroll
  for (int i = 0; i < 4; ++i)
    #pragma unroll
    for (int j = 0; j < 4; ++j) acc[i][j] = (f32x4)0.0f;

  for (int kt = 0; kt < DIM / 64; ++kt){
    const int k0 = kt * 64;
    #pragma unroll
    for (int c = 0; c < 4; ++c){
      int id  = c * 256 + t;
      int row = id >> 3;
      int cb  = (id & 7) * 8;
      g2l16(&As[row][cb], E + (size_t)(m0 + row) * DIM + k0 + cb);
      g2l16(&Bs[row][cb], W + (size_t)(n0 + row) * DIM + k0 + cb);
    }
    asm volatile("s_waitcnt vmcnt(0)" ::: "memory");
    __syncthreads();
    #pragma unroll
    for (int ks = 0; ks < 2; ++ks){
      bf16x8 af[4], bfr[4];
      #pragma unroll
      for (int i = 0; i < 4; ++i){
        af[i]  = *(const bf16x8*)&As[wr + i*16 + lr][ks*32 + lk*8];
        bfr[i] = *(const bf16x8*)&Bs[wc + i*16 + lr][ks*32 + lk*8];
      }
      #pragma unroll
      for (int i = 0; i < 4; ++i)
        #pragma unroll
        for (int j = 0; j < 4; ++j)
          acc[i][j] = mfma16(af[i], bfr[j], acc[i][j]);
    }
    __syncthreads();
  }
  #pragma unroll
  for (int i = 0; i < 4; ++i)
    #pragma unroll
    for (int j = 0; j < 4; ++j)
      #pragma unroll
      for (int r = 0; r < 4; ++r){
        int row = wr + i*16 + lk*4 + r;
        int col = wc + j*16 + lr;
        dst[(size_t)(m0 + row) * DIM + n0 + col] = f2bf(acc[i][j][r]);
      }
}

// ---------------- V transpose ----------------
__global__ __launch_bounds__(256) void transpose_v(
    const unsigned short* __restrict__ V, unsigned short* __restrict__ VT)
{
  __shared__ unsigned short T[64][72];
  const int b  = blockIdx.z;
  const int s0 = blockIdx.x * 64;
  const int a0 = blockIdx.y * 64;
  const unsigned short* Vb = V + (size_t)b * SEQ * DIM;
  unsigned short* VTb = VT + (size_t)b * DIM * SEQ;
  const int t = threadIdx.x;
  const int r = t >> 3, cg = t & 7;
  #pragma unroll
  for (int p = 0; p < 2; ++p){
    int row = r + p * 32;
    ushortx8 v = *(const ushortx8*)(Vb + (size_t)(s0 + row) * DIM + a0 + cg*8);
    *(ushortx8*)&T[row][cg*8] = v;
  }
  __syncthreads();
  #pragma unroll
  for (int p = 0; p < 2; ++p){
    int ar = r + p * 32;
    ushortx8 o;
    #pragma unroll
    for (int j = 0; j < 8; ++j) o[j] = T[cg*8 + j][ar];
    *(ushortx8*)(VTb + (size_t)(a0 + ar) * SEQ + s0 + cg*8) = o;
  }
}

// ---------------- S/P GEMM: P = exp(scale * Q K^T) (causal), packed tiles ----
// grid (32 tj, 32 ti, 4 b); blocks with tj > ti exit. gemm_qkv structure.
// Epilogue: causal mask, exp, bf16 write to packed tile (ti*(ti+1)/2+tj),
// and per-row partial sums atomicAdd'ed into lrow[].
__global__ __launch_bounds__(256, 2) void sp_gemm(
    const unsigned short* __restrict__ Q,
    const unsigned short* __restrict__ K,
    unsigned short* __restrict__ Sp,
    float* __restrict__ lrow)
{
  const int tj = blockIdx.x;
  const int ti = blockIdx.y;
  if (tj > ti) return;
  const int b  = blockIdx.z;

  __shared__ unsigned short As[128][64];
  __shared__ unsigned short Bs[128][64];

  const int t  = threadIdx.x;
  const int m0 = ti * 128;
  const int n0 = tj * 128;
  const unsigned short* A = Q + (size_t)b * SEQ * DIM;
  const unsigned short* B = K + (size_t)b * SEQ * DIM;

  const int l  = t & 63;
  const int w  = t >> 6;
  const int lr = l & 15;
  const int lk = l >> 4;
  const int wr = (w >> 1) * 64;
  const int wc = (w & 1) * 64;

  f32x4 acc[4][4];
  #pragma unroll
  for (int i = 0; i < 4; ++i)
    #pragma unroll
    for (int j = 0; j < 4; ++j) acc[i][j] = (f32x4)0.0f;

  for (int kt = 0; kt < DIM / 64; ++kt){
    const int k0 = kt * 64;
    #pragma unroll
    for (int c = 0; c < 4; ++c){
      int id  = c * 256 + t;
      int row = id >> 3;
      int cb  = (id & 7) * 8;
      g2l16(&As[row][cb], A + (size_t)(m0 + row) * DIM + k0 + cb);
      g2l16(&Bs[row][cb], B + (size_t)(n0 + row) * DIM + k0 + cb);
    }
    asm volatile("s_waitcnt vmcnt(0)" ::: "memory");
    __syncthreads();
    #pragma unroll
    for (int ks = 0; ks < 2; ++ks){
      bf16x8 af[4], bfr[4];
      #pragma unroll
      for (int i = 0; i < 4; ++i){
        af[i]  = *(const bf16x8*)&As[wr + i*16 + lr][ks*32 + lk*8];
        bfr[i] = *(const bf16x8*)&Bs[wc + i*16 + lr][ks*32 + lk*8];
      }
      #pragma unroll
      for (int i = 0; i < 4; ++i)
        #pragma unroll
        for (int j = 0; j < 4; ++j)
          acc[i][j] = mfma16(af[i], bfr[j], acc[i][j]);
    }
    __syncthreads();
  }

  // epilogue: P = exp(scale*acc) masked; bf16 packed write; row-sum atomics
  const float scale = 0.03125f;  // 1/sqrt(1024)
  unsigned short* tile =
      Sp + ((size_t)b * TRI + (size_t)(ti * (ti + 1) / 2) + tj) * 16384;
  float* lb = lrow + (size_t)b * SEQ + m0;

  #pragma unroll
  for (int i = 0; i < 4; ++i){
    float rs[4] = {0.f, 0.f, 0.f, 0.f};
    #pragma unroll
    for (int j = 0; j < 4; ++j){
      #pragma unroll
      for (int r = 0; r < 4; ++r){
        int row = wr + i*16 + lk*4 + r;
        int col = wc + j*16 + lr;
        float p = 0.0f;
        if (n0 + col <= m0 + row) p = __expf(acc[i][j][r] * scale);
        rs[r] += p;
        tile[row * 128 + col] = f2bf(p);
      }
    }
    #pragma unroll
    for (int r = 0; r < 4; ++r){
      float v = rs[r];
      v += __shfl_xor(v, 1, 64);
      v += __shfl_xor(v, 2, 64);
      v += __shfl_xor(v, 4, 64);
      v += __shfl_xor(v, 8, 64);
      if (lr == 0)
        atomicAdd(&lb[wr + i*16 + lk*4 + r], v);
    }
  }
}

// ---------------- PV GEMM: O = (P V) / l. A = packed P, B = VT (B^T layout) ----
// grid (8 nx, 16 pair, 4 b). Each block: M-tiles ti = 31-pair then pair
// (66 K-steps total -> perfectly balanced). gemm_qkv structure.
__global__ __launch_bounds__(256, 2) void pv_gemm(
    const unsigned short* __restrict__ Sp,
    const unsigned short* __restrict__ VT,
    const float* __restrict__ lrow,
    float* __restrict__ out)
{
  __shared__ unsigned short As[128][64];
  __shared__ unsigned short Bs[128][64];

  const int nx = blockIdx.x;
  const int pr = blockIdx.y;
  const int b  = blockIdx.z;
  const int t  = threadIdx.x;

  const int l  = t & 63;
  const int w  = t >> 6;
  const int lr = l & 15;
  const int lk = l >> 4;
  const int wr = (w >> 1) * 64;
  const int wc = (w & 1) * 64;

  const int n0 = nx * 128;
  const unsigned short* VTb = VT + (size_t)b * DIM * SEQ;
  const unsigned short* Spb = Sp + (size_t)b * TRI * 16384;

  for (int half = 0; half < 2; ++half){
    const int ti = half ? pr : (31 - pr);
    const int m0 = ti * 128;
    const unsigned short* Pt = Spb + (size_t)(ti * (ti + 1) / 2) * 16384;
    const int ksteps = 2 * (ti + 1);

    f32x4 acc[4][4];
    #pragma unroll
    for (int i = 0; i < 4; ++i)
      #pragma unroll
      for (int j = 0; j < 4; ++j) acc[i][j] = (f32x4)0.0f;

    for (int s = 0; s < ksteps; ++s){
      #pragma unroll
      for (int c = 0; c < 4; ++c){
        int id  = c * 256 + t;
        int row = id >> 3;
        int cb  = (id & 7) * 8;
        g2l16(&As[row][cb],
              Pt + (size_t)(s >> 1) * 16384 + row * 128 + (s & 1) * 64 + cb);
        g2l16(&Bs[row][cb],
              VTb + (size_t)(n0 + row) * SEQ + s * 64 + cb);
      }
      asm volatile("s_waitcnt vmcnt(0)" ::: "memory");
      __syncthreads();
      #pragma unroll
      for (int ks = 0; ks < 2; ++ks){
        bf16x8 af[4], bfr[4];
        #pragma unroll
        for (int i = 0; i < 4; ++i){
          af[i]  = *(const bf16x8*)&As[wr + i*16 + lr][ks*32 + lk*8];
          bfr[i] = *(const bf16x8*)&Bs[wc + i*16 + lr][ks*32 + lk*8];
        }
        #pragma unroll
        for (int i = 0; i < 4; ++i)
          #pragma unroll
          for (int j = 0; j < 4; ++j)
            acc[i][j] = mfma16(af[i], bfr[j], acc[i][j]);
      }
      __syncthreads();
    }

    const float* lb = lrow + (size_t)b * SEQ + m0;
    float* ob = out + ((size_t)b * SEQ + m0) * DIM + n0;
    #pragma unroll
    for (int i = 0; i < 4; ++i)
      #pragma unroll
      for (int r = 0; r < 4; ++r){
        int row = wr + i*16 + lk*4 + r;
        float inv = 1.0f / lb[row];
        #pragma unroll
        for (int j = 0; j < 4; ++j)
          ob[(size_t)row * DIM + wc + j*16 + lr] = acc[i][j][r] * inv;
      }
  }
}

// ---------------- launch ----------------
extern "C" void kernel_launch(void* const* d_in, const int* in_sizes, int n_in,
                              void* d_out, int out_size, void* d_ws, size_t ws_size,
                              hipStream_t stream)
{
  (void)in_sizes; (void)n_in; (void)out_size; (void)ws_size;
  const float* emb = (const float*)d_in[0];
  const float* Wq  = (const float*)d_in[1];
  const float* Wk  = (const float*)d_in[2];
  const float* Wv  = (const float*)d_in[3];

  char* ws = (char*)d_ws;
  unsigned short* EB = (unsigned short*)ws;                    // 32MB (reused as VT)
  unsigned short* WB = (unsigned short*)(ws + 33554432);       // 6MB: Wq|Wk|Wv bf16
  unsigned short* Qb = (unsigned short*)(ws + 39845888);       // 32MB
  unsigned short* Kb = (unsigned short*)(ws + 73400320);       // 32MB
  unsigned short* Sp = (unsigned short*)(ws + 106954752);      // 66MB packed P tiles
  float*          lr = (float*)(ws + 176160768);               // 64KB row sums
  unsigned short* Vb = (unsigned short*)d_out;                 // V scratch in out buffer
  unsigned short* VT = EB;                                     // alias: E dead after gemm

  hipMemsetAsync(lr, 0, (size_t)NB * SEQ * sizeof(float), stream);

  cvt_kernel<<<16384, 256, 0, stream>>>(emb, EB, 4194304);
  cvt_kernel<<<1024, 256, 0, stream>>>(Wq, WB,           262144);
  cvt_kernel<<<1024, 256, 0, stream>>>(Wk, WB + 1048576, 262144);
  cvt_kernel<<<1024, 256, 0, stream>>>(Wv, WB + 2097152, 262144);

  gemm_qkv<<<dim3(8, 128, 3), 256, 0, stream>>>(EB, WB, Qb, Kb, Vb);
  transpose_v<<<dim3(64, 16, 4), 256, 0, stream>>>(Vb, VT);

  sp_gemm<<<dim3(32, 32, 4), 256, 0, stream>>>(Qb, Kb, Sp, lr);
  pv_gemm<<<dim3(8, 16, 4), 256, 0, stream>>>(Sp, VT, lr, (float*)d_out);
}